// Round 1
// baseline (34.067 us; speedup 1.0000x reference)
//
#include <hip/hip_runtime.h>
#include <hip/hip_bf16.h>

// Problem constants (fixed by setup_inputs)
constexpr int B  = 32;
constexpr int H  = 640;
constexpr int Wd = 640;
constexpr int M  = 256;

constexpr int CHUNKS       = 100;               // blocks per image
constexpr int F4_PER_IMG   = H * Wd / 4;        // 102400
constexpr int F4_PER_BLOCK = F4_PER_IMG / CHUNKS; // 1024 float4 per block
constexpr int NBLK         = B * CHUNKS;        // 3200 blocks in main kernel

// Workspace layout (bytes):
//   [0,128)            : int counts[B]
//   [256, 256+65536)   : ushort4 lists[B][M]  (x1,y1,x2,y2)
//   [65792, +NBLK*4)   : float partials[NBLK]
constexpr size_t WS_LISTS_OFF    = 256;
constexpr size_t WS_PARTIALS_OFF = 256 + (size_t)B * M * 8;

// ---------------------------------------------------------------------------
// Kernel 1: compute integer box coords (bit-identical to the JAX f32 math)
// and bucket into per-image lists. One block, 256 threads.
// ---------------------------------------------------------------------------
__global__ __launch_bounds__(256) void build_box_lists(
    const float* __restrict__ bboxes, const int* __restrict__ batch_idx,
    int* __restrict__ counts, ushort4* __restrict__ lists)
{
    int t = threadIdx.x;
    if (t < B) counts[t] = 0;
    __syncthreads();
    if (t < M) {
        float cx = bboxes[t * 4 + 0] * 640.0f;
        float cy = bboxes[t * 4 + 1] * 640.0f;
        float bw = bboxes[t * 4 + 2] * 640.0f;
        float bh = bboxes[t * 4 + 3] * 640.0f;
        // clip(v, 0, dim-1) then truncate toward zero (values >= 0 -> floor)
        float x1f = fminf(fmaxf(cx - bw * 0.5f, 0.0f), 639.0f);
        float y1f = fminf(fmaxf(cy - bh * 0.5f, 0.0f), 639.0f);
        float x2f = fminf(fmaxf(cx + bw * 0.5f, 0.0f), 639.0f);
        float y2f = fminf(fmaxf(cy + bh * 0.5f, 0.0f), 639.0f);
        ushort4 bx;
        bx.x = (unsigned short)(int)x1f;
        bx.y = (unsigned short)(int)y1f;
        bx.z = (unsigned short)(int)x2f;
        bx.w = (unsigned short)(int)y2f;
        int img  = batch_idx[t];
        int slot = atomicAdd(&counts[img], 1);   // order irrelevant: union
        lists[img * M + slot] = bx;
    }
}

// ---------------------------------------------------------------------------
// Kernel 2: streaming BCE partial sums. Each block handles 1024 float4
// (4096 pixels) of one image; boxes of that image row-filtered into LDS.
// ---------------------------------------------------------------------------
__global__ __launch_bounds__(256) void bce_partial(
    const float* __restrict__ seg_preds,
    const int* __restrict__ counts,
    const ushort4* __restrict__ lists,
    const unsigned char* __restrict__ is_seg,
    float* __restrict__ partials)
{
    const int img   = blockIdx.x / CHUNKS;
    const int chunk = blockIdx.x % CHUNKS;

    __shared__ ushort4 sbox[M];
    __shared__ int scount;
    __shared__ float wsum[4];

    const int cnt = counts[img];
    // pixel range of this block within the image -> row range
    const int p_start = chunk * F4_PER_BLOCK * 4;
    const int row_lo  = p_start / Wd;
    const int row_hi  = (p_start + F4_PER_BLOCK * 4 - 1) / Wd;

    if (threadIdx.x == 0) scount = 0;
    __syncthreads();
    for (int i = threadIdx.x; i < cnt; i += 256) {
        ushort4 bx = lists[img * M + i];
        if ((int)bx.y <= row_hi && (int)bx.w >= row_lo) {
            int slot = atomicAdd(&scount, 1);
            sbox[slot] = bx;
        }
    }
    __syncthreads();
    const int  ncnt = scount;
    const bool det  = (is_seg[img] == 0);   // detection image -> mask active

    const float4* __restrict__ xin =
        (const float4*)(seg_preds + (size_t)img * H * Wd);

    float acc = 0.0f;
    #pragma unroll
    for (int k = 0; k < 4; ++k) {
        const int   f4 = chunk * F4_PER_BLOCK + k * 256 + threadIdx.x;
        const float4 v = xin[f4];
        const int p   = f4 * 4;
        const int row = p / Wd;     // compiler magic-div (constant)
        const int col = p - row * Wd;

        unsigned covm = 0u;          // 4-bit coverage mask for the 4 pixels
        if (det) {
            for (int i = 0; i < ncnt; ++i) {
                ushort4 bx = sbox[i];
                if (row >= (int)bx.y && row <= (int)bx.w) {
                    int lo = max((int)bx.x - col, 0);
                    int hi = min((int)bx.z - col, 3);
                    if (lo <= hi) covm |= ((1u << (hi - lo + 1)) - 1u) << lo;
                    if (covm == 0xFu) break;
                }
            }
        }
        const float vals[4] = {v.x, v.y, v.z, v.w};
        #pragma unroll
        for (int j = 0; j < 4; ++j) {
            float xv = vals[j];
            float a  = fabsf(xv);
            // log1p(exp(-a)) via native exp/log; |err| < ~1.5e-7 absolute
            float sp = __logf(1.0f + __expf(-a));
            float term = fmaxf(xv, 0.0f) + sp;
            if (covm & (1u << j)) term -= xv;   // -x*y with y==1
            acc += term;
        }
    }

    // wave (64) reduce, then across the 4 waves
    for (int off = 32; off > 0; off >>= 1)
        acc += __shfl_down(acc, off, 64);
    const int lane = threadIdx.x & 63;
    const int wid  = threadIdx.x >> 6;
    if (lane == 0) wsum[wid] = acc;
    __syncthreads();
    if (threadIdx.x == 0)
        partials[blockIdx.x] = wsum[0] + wsum[1] + wsum[2] + wsum[3];
}

// ---------------------------------------------------------------------------
// Kernel 3: deterministic f64 reduction of partials -> final scalar.
// ---------------------------------------------------------------------------
__global__ __launch_bounds__(256) void finalize(
    const float* __restrict__ partials,
    const unsigned char* __restrict__ is_seg,
    float* __restrict__ out)
{
    __shared__ double sd[256];
    double s = 0.0;
    for (int i = threadIdx.x; i < NBLK; i += 256) s += (double)partials[i];
    sd[threadIdx.x] = s;
    __syncthreads();
    for (int off = 128; off > 0; off >>= 1) {
        if (threadIdx.x < off) sd[threadIdx.x] += sd[threadIdx.x + off];
        __syncthreads();
    }
    if (threadIdx.x == 0) {
        int nd = 0;
        for (int b = 0; b < B; ++b) nd += (is_seg[b] == 0) ? 1 : 0;
        double hd   = (nd > 0) ? 1.0 : 0.0;
        double mean = sd[0] / (double)((size_t)B * H * Wd);
        out[0] = (float)(0.1 * mean * hd);
    }
}

extern "C" void kernel_launch(void* const* d_in, const int* in_sizes, int n_in,
                              void* d_out, int out_size, void* d_ws, size_t ws_size,
                              hipStream_t stream)
{
    const float*         seg_preds = (const float*)d_in[0];
    const float*         bboxes    = (const float*)d_in[1];
    const int*           batch_idx = (const int*)d_in[2];
    const unsigned char* is_seg    = (const unsigned char*)d_in[3]; // all-false bools

    int*     counts   = (int*)d_ws;
    ushort4* lists    = (ushort4*)((char*)d_ws + WS_LISTS_OFF);
    float*   partials = (float*)((char*)d_ws + WS_PARTIALS_OFF);
    float*   out      = (float*)d_out;

    build_box_lists<<<1, 256, 0, stream>>>(bboxes, batch_idx, counts, lists);
    bce_partial<<<NBLK, 256, 0, stream>>>(seg_preds, counts, lists, is_seg, partials);
    finalize<<<1, 256, 0, stream>>>(partials, is_seg, out);
}